// Round 2
// baseline (343.930 us; speedup 1.0000x reference)
//
#include <hip/hip_runtime.h>

// Problem constants (fixed by reference)
constexpr int B_   = 8;
constexpr int N_   = 2048;
constexpr int CIN_ = 128;
constexpr int F1_  = 256;
constexpr int F2_  = 256;
constexpr int F3_  = 64;
constexpr int M_   = B_ * N_;   // 16384 tokens

// ---------------------------------------------------------------------------
// Generic tiled GEMM: C[m][f] = act( sum_k A[m][k] * W[f][k] + bias[f] )
// BM=BF=64, BK=16, 256 threads, 4x4 register tile per thread.
// ---------------------------------------------------------------------------
template<int RELU>
__global__ __launch_bounds__(256)
void gemm_bias_act(const float* __restrict__ A, const float* __restrict__ W,
                   const float* __restrict__ bias, float* __restrict__ C,
                   int K, int F)
{
    __shared__ __align__(16) float As[16][64];
    __shared__ __align__(16) float Ws[16][64];
    const int tid = threadIdx.x;
    const int tx = tid & 15, ty = tid >> 4;
    const int m0 = blockIdx.y * 64, f0 = blockIdx.x * 64;
    const int lr = tid >> 2;          // 0..63 (tile row)
    const int lc = (tid & 3) << 2;    // 0,4,8,12 (k offset)

    float acc[4][4] = {};
    for (int k0 = 0; k0 < K; k0 += 16) {
        float4 av = *(const float4*)(A + (size_t)(m0 + lr) * K + (k0 + lc));
        float4 wv = *(const float4*)(W + (size_t)(f0 + lr) * K + (k0 + lc));
        As[lc+0][lr] = av.x; As[lc+1][lr] = av.y; As[lc+2][lr] = av.z; As[lc+3][lr] = av.w;
        Ws[lc+0][lr] = wv.x; Ws[lc+1][lr] = wv.y; Ws[lc+2][lr] = wv.z; Ws[lc+3][lr] = wv.w;
        __syncthreads();
#pragma unroll
        for (int k = 0; k < 16; ++k) {
            const float4 a4 = *(const float4*)&As[k][ty << 2];
            const float4 w4 = *(const float4*)&Ws[k][tx << 2];
            const float aa[4] = {a4.x, a4.y, a4.z, a4.w};
            const float ww[4] = {w4.x, w4.y, w4.z, w4.w};
#pragma unroll
            for (int i = 0; i < 4; ++i)
#pragma unroll
                for (int j = 0; j < 4; ++j)
                    acc[i][j] = fmaf(aa[i], ww[j], acc[i][j]);
        }
        __syncthreads();
    }
    const float4 bz = *(const float4*)(bias + f0 + (tx << 2));
#pragma unroll
    for (int i = 0; i < 4; ++i) {
        float4 o;
        o.x = acc[i][0] + bz.x; o.y = acc[i][1] + bz.y;
        o.z = acc[i][2] + bz.z; o.w = acc[i][3] + bz.w;
        if (RELU) {
            o.x = fmaxf(o.x, 0.f); o.y = fmaxf(o.y, 0.f);
            o.z = fmaxf(o.z, 0.f); o.w = fmaxf(o.w, 0.f);
        }
        *(float4*)(C + (size_t)(m0 + (ty << 2) + i) * F + f0 + (tx << 2)) = o;
    }
}

// ---------------------------------------------------------------------------
// sq[t] = ||u[t]||^2
// ---------------------------------------------------------------------------
__global__ __launch_bounds__(256)
void sq_kernel(const float* __restrict__ u, float* __restrict__ sq)
{
    int id = blockIdx.x * 256 + threadIdx.x;
    const float4* r = (const float4*)(u + (size_t)id * F3_);
    float s = 0.f;
#pragma unroll
    for (int q = 0; q < 16; ++q) {
        float4 v = r[q];
        s += v.x*v.x + v.y*v.y + v.z*v.z + v.w*v.w;
    }
    sq[id] = s;
}

// ---------------------------------------------------------------------------
// Adjacency bitset: bit(b,i,j) = ( sq_i + sq_j - 2*dot(u_i,u_j) <= 1.0 )
// Layout word-major for coalesced CC scans: adj[b][w][i], w = j/32 (64 words).
// One block computes a 64x64 tile of one batch's matrix.
// ---------------------------------------------------------------------------
__global__ __launch_bounds__(256)
void adj_kernel(const float* __restrict__ u, const float* __restrict__ sq,
                unsigned* __restrict__ adj)
{
    __shared__ __align__(16) float Uis[64][64];
    __shared__ __align__(16) float Ujs[64][64];
    __shared__ float sqi[64], sqj[64];
    __shared__ unsigned bw[64][2];
    const int tid = threadIdx.x;
    const int tx = tid & 15, ty = tid >> 4;
    const int jt = blockIdx.x, it = blockIdx.y, b = blockIdx.z;
    const int i0 = it * 64, j0 = jt * 64;
    const size_t ubase = (size_t)b * N_;

    if (tid < 128) bw[tid >> 1][tid & 1] = 0u;
#pragma unroll
    for (int q = 0; q < 4; ++q) {
        int t = tid + q * 256;
        int r = t >> 4;            // 0..63
        int c = (t & 15) << 2;     // 0..60
        float4 vi = *(const float4*)(u + (ubase + i0 + r) * F3_ + c);
        float4 vj = *(const float4*)(u + (ubase + j0 + r) * F3_ + c);
        Uis[c+0][r] = vi.x; Uis[c+1][r] = vi.y; Uis[c+2][r] = vi.z; Uis[c+3][r] = vi.w;
        Ujs[c+0][r] = vj.x; Ujs[c+1][r] = vj.y; Ujs[c+2][r] = vj.z; Ujs[c+3][r] = vj.w;
    }
    if (tid < 64) { sqi[tid] = sq[ubase + i0 + tid]; sqj[tid] = sq[ubase + j0 + tid]; }
    __syncthreads();

    float acc[4][4] = {};
#pragma unroll
    for (int k = 0; k < 64; ++k) {
        const float4 a4 = *(const float4*)&Uis[k][ty << 2];
        const float4 b4 = *(const float4*)&Ujs[k][tx << 2];
        const float aa[4] = {a4.x, a4.y, a4.z, a4.w};
        const float bb[4] = {b4.x, b4.y, b4.z, b4.w};
#pragma unroll
        for (int i = 0; i < 4; ++i)
#pragma unroll
            for (int j = 0; j < 4; ++j)
                acc[i][j] = fmaf(aa[i], bb[j], acc[i][j]);
    }

    const unsigned wl = tx >> 3;
    const unsigned sh = (tx & 7) << 2;
#pragma unroll
    for (int i = 0; i < 4; ++i) {
        int r = (ty << 2) + i;
        unsigned nib = 0u;
#pragma unroll
        for (int j = 0; j < 4; ++j) {
            float d = sqi[r] + sqj[(tx << 2) + j] - 2.f * acc[i][j];
            if (d <= 1.0f) nib |= (1u << j);
        }
        atomicOr(&bw[r][wl], nib << sh);
    }
    __syncthreads();
    if (tid < 128) {
        int wl2 = tid >> 6;         // 0..1
        int r   = tid & 63;
        int w   = (jt << 1) + wl2;  // absolute word index 0..63
        adj[((size_t)b * 64 + w) * N_ + i0 + r] = bw[r][wl2];
    }
}

// ---------------------------------------------------------------------------
// Connected components via max-label propagation.
// Labels are per-batch node indices; invariant L[i] >= i, L[i] in comp(i).
// Each round: hook (max over bitset neighbors) + capped pointer-jump walk.
// 8 rounds x 256-step walks guarantee convergence for any 2048-node graph
// (worst case path graph: ~258 positions/round x 8 = 2064 > 2047).
// ---------------------------------------------------------------------------
__global__ __launch_bounds__(256)
void init_kernel(int* __restrict__ L0, float* __restrict__ loss)
{
    int id = blockIdx.x * 256 + threadIdx.x;
    L0[id] = id & (N_ - 1);
    if (id == 0) *loss = 0.f;
}

__global__ __launch_bounds__(256)
void cc_round(const unsigned* __restrict__ adj, const int* __restrict__ Lin,
              int* __restrict__ Lout)
{
    int id = blockIdx.x * 256 + threadIdx.x;
    int b = id >> 11;
    int i = id & (N_ - 1);
    const int* Lb = Lin + (b << 11);
    int m = Lb[i];
    const unsigned* row = adj + (size_t)b * 64 * N_ + i;
#pragma unroll 4
    for (int w = 0; w < 64; ++w) {
        unsigned v = row[(size_t)w * N_];
        while (v) {
            int bit = __ffs(v) - 1;
            v &= v - 1;
            int lj = Lb[(w << 5) + bit];
            m = (lj > m) ? lj : m;
        }
    }
    // pointer-jump walk (labels strictly increase along chain), capped
#pragma unroll 1
    for (int q = 0; q < 256; ++q) {
        int t = Lb[m];
        if (t == m) break;
        m = t;
    }
    Lout[id] = m;
}

__global__ __launch_bounds__(256)
void finalize_kernel(const int* __restrict__ L, float* __restrict__ out)
{
    int id = blockIdx.x * 256 + threadIdx.x;
    out[id] = (float)L[id];
}

__global__ __launch_bounds__(256)
void sentinel_kernel(float* out, int n)
{
    int id = blockIdx.x * 256 + threadIdx.x;
    if (id < n) out[id] = -777.0f;
}

// ---------------------------------------------------------------------------
// Triplet loss: one block per batch; thread t handles triplet t (200 < 256).
// ---------------------------------------------------------------------------
__global__ __launch_bounds__(256)
void loss_kernel(const float* __restrict__ u, const float* __restrict__ sq,
                 const int* __restrict__ labels, const int* __restrict__ tri,
                 float* __restrict__ loss)
{
    __shared__ float ssum[256];
    __shared__ int   scnt[256];
    __shared__ int   smax[256];
    const int b = blockIdx.x, t = threadIdx.x;
    const int base = b << 11;

    float mysum = 0.f; int mycnt = 0;
    if (t < 200) {
        int a = tri[3*t+0], p = tri[3*t+1], n = tri[3*t+2];
        int la = labels[base+a], lp = labels[base+p], ln = labels[base+n];
        bool valid = (a != p) && (la == lp) && (lp != ln);
        const float4* ua = (const float4*)(u + (size_t)(base + a) * F3_);
        const float4* up = (const float4*)(u + (size_t)(base + p) * F3_);
        const float4* un = (const float4*)(u + (size_t)(base + n) * F3_);
        float dap = 0.f, dan = 0.f;
#pragma unroll
        for (int q = 0; q < 16; ++q) {
            float4 va = ua[q], vp = up[q], vn = un[q];
            dap += va.x*vp.x + va.y*vp.y + va.z*vp.z + va.w*vp.w;
            dan += va.x*vn.x + va.y*vn.y + va.z*vn.z + va.w*vn.w;
        }
        float d1 = fmaxf(sq[base+a] + sq[base+p] - 2.f*dap, 0.f);
        float d2 = fmaxf(sq[base+a] + sq[base+n] - 2.f*dan, 0.f);
        float tt = fmaxf(d1 - d2 + 2.0f, 0.f);
        if (valid) { mysum = tt; mycnt = 1; }
    }
    int mymax = 0;
    for (int idx = t; idx < N_; idx += 256) {
        int lv = labels[base + idx];
        mymax = (lv > mymax) ? lv : mymax;
    }
    ssum[t] = mysum; scnt[t] = mycnt; smax[t] = mymax;
    __syncthreads();
    for (int s = 128; s > 0; s >>= 1) {
        if (t < s) {
            ssum[t] += ssum[t + s];
            scnt[t] += scnt[t + s];
            smax[t] = (smax[t + s] > smax[t]) ? smax[t + s] : smax[t];
        }
        __syncthreads();
    }
    if (t == 0) {
        int cnt = scnt[0];
        bool use = (smax[0] > 0) && (cnt > 0);
        float contrib = use ? (ssum[0] / (float)(cnt > 1 ? cnt : 1)) : 0.f;
        atomicAdd(loss, contrib);
    }
}

// ---------------------------------------------------------------------------
extern "C" void kernel_launch(void* const* d_in, const int* in_sizes, int n_in,
                              void* d_out, int out_size, void* d_ws, size_t ws_size,
                              hipStream_t stream)
{
    const float* x      = (const float*)d_in[0];
    const int*   labels = (const int*)  d_in[1];
    const int*   tri    = (const int*)  d_in[2];
    const float* W1     = (const float*)d_in[3];
    const float* b1     = (const float*)d_in[4];
    const float* W2     = (const float*)d_in[5];
    const float* b2     = (const float*)d_in[6];
    const float* W3     = (const float*)d_in[7];
    const float* b3     = (const float*)d_in[8];
    float* out = (float*)d_out;

    char* w = (char*)d_ws;
    size_t off = 0;
    auto carve = [&](size_t bytes) -> char* {
        char* p = w + off;
        off += (bytes + 255) & ~(size_t)255;
        return p;
    };
    float*    h1   = (float*)   carve((size_t)M_ * F1_ * 4);
    float*    h2   = (float*)   carve((size_t)M_ * F2_ * 4);
    float*    u    = (float*)   carve((size_t)M_ * F3_ * 4);
    float*    sq   = (float*)   carve((size_t)M_ * 4);
    unsigned* adj  = (unsigned*)carve((size_t)B_ * 64 * N_ * 4);
    int*      lab0 = (int*)     carve((size_t)M_ * 4);
    int*      lab1 = (int*)     carve((size_t)M_ * 4);

    if (off > ws_size) {
        // ws too small — emit sentinel so the failure mode is diagnosable
        hipLaunchKernelGGL(sentinel_kernel, dim3((out_size + 255) / 256), dim3(256),
                           0, stream, out, out_size);
        return;
    }

    hipLaunchKernelGGL(init_kernel, dim3(M_ / 256), dim3(256), 0, stream,
                       lab0, out + M_);

    hipLaunchKernelGGL((gemm_bias_act<1>), dim3(F1_ / 64, M_ / 64), dim3(256), 0, stream,
                       x,  W1, b1, h1, CIN_, F1_);
    hipLaunchKernelGGL((gemm_bias_act<1>), dim3(F2_ / 64, M_ / 64), dim3(256), 0, stream,
                       h1, W2, b2, h2, F1_,  F2_);
    hipLaunchKernelGGL((gemm_bias_act<0>), dim3(F3_ / 64, M_ / 64), dim3(256), 0, stream,
                       h2, W3, b3, u,  F2_,  F3_);

    hipLaunchKernelGGL(sq_kernel, dim3(M_ / 256), dim3(256), 0, stream, u, sq);

    hipLaunchKernelGGL(adj_kernel, dim3(N_ / 64, N_ / 64, B_), dim3(256), 0, stream,
                       u, sq, adj);

    hipLaunchKernelGGL(loss_kernel, dim3(B_), dim3(256), 0, stream,
                       u, sq, labels, tri, out + M_);

    int* bufs[2] = {lab0, lab1};
    for (int r = 0; r < 8; ++r)
        hipLaunchKernelGGL(cc_round, dim3(M_ / 256), dim3(256), 0, stream,
                           adj, bufs[r & 1], bufs[(r + 1) & 1]);

    hipLaunchKernelGGL(finalize_kernel, dim3(M_ / 256), dim3(256), 0, stream,
                       lab0, out);
}

// Round 3
// 257.255 us; speedup vs baseline: 1.3369x; 1.3369x over previous
//
#include <hip/hip_runtime.h>

// Problem constants (fixed by reference)
constexpr int B_   = 8;
constexpr int N_   = 2048;
constexpr int CIN_ = 128;
constexpr int F1_  = 256;
constexpr int F2_  = 256;
constexpr int F3_  = 64;
constexpr int M_   = B_ * N_;   // 16384 tokens

// ---------------------------------------------------------------------------
// GEMM: C[m][f] = act( sum_k A[m][k] * W[f][k] + bias[f] )
// 128xTF tile, BK=32, 256 threads, 8x(TF/16) register tile per thread.
// LDS padded to 132 floats/row -> 16B-aligned rows, reduced write conflicts.
// ---------------------------------------------------------------------------
template<int TF, int RELU>
__global__ __launch_bounds__(256, 4)
void gemm_bias_act(const float* __restrict__ A, const float* __restrict__ W,
                   const float* __restrict__ bias, float* __restrict__ C,
                   int K, int F)
{
    constexpr int WF = TF / 16;           // 8 or 4 cols per thread
    __shared__ __align__(16) float As[32][132];
    __shared__ __align__(16) float Ws[32][TF + 4];
    const int tid = threadIdx.x;
    const int tx = tid & 15, ty = tid >> 4;
    const int m0 = blockIdx.y * 128, f0 = blockIdx.x * TF;

    float acc[8][WF] = {};
    for (int k0 = 0; k0 < K; k0 += 32) {
        __syncthreads();
#pragma unroll
        for (int p = 0; p < 4; ++p) {
            int idx = tid + p * 256;
            int r = idx >> 3, c = (idx & 7) << 2;
            float4 v = *(const float4*)(A + (size_t)(m0 + r) * K + k0 + c);
            As[c+0][r] = v.x; As[c+1][r] = v.y; As[c+2][r] = v.z; As[c+3][r] = v.w;
        }
#pragma unroll
        for (int p = 0; p < TF / 32; ++p) {
            int idx = tid + p * 256;
            int r = idx >> 3, c = (idx & 7) << 2;
            float4 v = *(const float4*)(W + (size_t)(f0 + r) * K + k0 + c);
            Ws[c+0][r] = v.x; Ws[c+1][r] = v.y; Ws[c+2][r] = v.z; Ws[c+3][r] = v.w;
        }
        __syncthreads();
#pragma unroll
        for (int k = 0; k < 32; ++k) {
            float a[8], w[WF];
            *(float4*)&a[0] = *(const float4*)&As[k][ty * 8];
            *(float4*)&a[4] = *(const float4*)&As[k][ty * 8 + 4];
            *(float4*)&w[0] = *(const float4*)&Ws[k][tx * WF];
            if constexpr (WF == 8)
                *(float4*)&w[4] = *(const float4*)&Ws[k][tx * WF + 4];
#pragma unroll
            for (int i = 0; i < 8; ++i)
#pragma unroll
                for (int j = 0; j < WF; ++j)
                    acc[i][j] = fmaf(a[i], w[j], acc[i][j]);
        }
    }
    float bz[WF];
    *(float4*)&bz[0] = *(const float4*)(bias + f0 + tx * WF);
    if constexpr (WF == 8)
        *(float4*)&bz[4] = *(const float4*)(bias + f0 + tx * WF + 4);
#pragma unroll
    for (int i = 0; i < 8; ++i) {
        float o[WF];
#pragma unroll
        for (int j = 0; j < WF; ++j) {
            o[j] = acc[i][j] + bz[j];
            if (RELU) o[j] = fmaxf(o[j], 0.f);
        }
        float* cp = C + (size_t)(m0 + ty * 8 + i) * F + f0 + tx * WF;
        *(float4*)cp = *(const float4*)&o[0];
        if constexpr (WF == 8)
            *(float4*)(cp + 4) = *(const float4*)&o[4];
    }
}

// ---------------------------------------------------------------------------
// sq[t] = ||u[t]||^2  (+ zero the loss accumulator, which lives in d_out)
// ---------------------------------------------------------------------------
__global__ __launch_bounds__(256)
void sq_loss_init(const float* __restrict__ u, float* __restrict__ sq,
                  float* __restrict__ loss)
{
    int id = blockIdx.x * 256 + threadIdx.x;
    if (id == 0) *loss = 0.f;
    const float4* r = (const float4*)(u + (size_t)id * F3_);
    float s = 0.f;
#pragma unroll
    for (int q = 0; q < 16; ++q) {
        float4 v = r[q];
        s += v.x*v.x + v.y*v.y + v.z*v.z + v.w*v.w;
    }
    sq[id] = s;
}

// ---------------------------------------------------------------------------
// Adjacency bitset: bit(b,i,j) = ( sq_i + sq_j - 2*dot(u_i,u_j) <= 1.0 )
// 128x128 tile per block, BK=32 (2 iters over K=64), 8x8 frags.
// Output layout word-major: adj[b][w][i], w = j/32 (64 words per row).
// ---------------------------------------------------------------------------
__global__ __launch_bounds__(256, 4)
void adj_kernel(const float* __restrict__ u, const float* __restrict__ sq,
                unsigned* __restrict__ adj)
{
    __shared__ __align__(16) float Ui[32][132];
    __shared__ __align__(16) float Uj[32][132];
    __shared__ float sqi[128], sqj[128];
    __shared__ __align__(16) unsigned bw[128][4];
    const int tid = threadIdx.x;
    const int tx = tid & 15, ty = tid >> 4;
    const int jt = blockIdx.x, it = blockIdx.y, b = blockIdx.z;
    const int i0 = it * 128, j0 = jt * 128;
    const size_t ubase = (size_t)b * N_;

    if (tid < 128) { sqi[tid] = sq[ubase + i0 + tid]; sqj[tid] = sq[ubase + j0 + tid]; }
    ((uint2*)bw)[tid] = make_uint2(0u, 0u);   // zero 512 words

    float acc[8][8] = {};
    for (int kk = 0; kk < 64; kk += 32) {
        __syncthreads();
#pragma unroll
        for (int p = 0; p < 4; ++p) {
            int idx = tid + p * 256;
            int r = idx >> 3, c = (idx & 7) << 2;
            float4 vi = *(const float4*)(u + (ubase + i0 + r) * F3_ + kk + c);
            float4 vj = *(const float4*)(u + (ubase + j0 + r) * F3_ + kk + c);
            Ui[c+0][r] = vi.x; Ui[c+1][r] = vi.y; Ui[c+2][r] = vi.z; Ui[c+3][r] = vi.w;
            Uj[c+0][r] = vj.x; Uj[c+1][r] = vj.y; Uj[c+2][r] = vj.z; Uj[c+3][r] = vj.w;
        }
        __syncthreads();
#pragma unroll
        for (int k = 0; k < 32; ++k) {
            float a[8], w[8];
            *(float4*)&a[0] = *(const float4*)&Ui[k][ty * 8];
            *(float4*)&a[4] = *(const float4*)&Ui[k][ty * 8 + 4];
            *(float4*)&w[0] = *(const float4*)&Uj[k][tx * 8];
            *(float4*)&w[4] = *(const float4*)&Uj[k][tx * 8 + 4];
#pragma unroll
            for (int i = 0; i < 8; ++i)
#pragma unroll
                for (int j = 0; j < 8; ++j)
                    acc[i][j] = fmaf(a[i], w[j], acc[i][j]);
        }
    }

    const int wl = tx >> 2;
    const int sh = (tx & 3) << 3;
#pragma unroll
    for (int i = 0; i < 8; ++i) {
        int r = ty * 8 + i;
        unsigned msk = 0u;
#pragma unroll
        for (int j = 0; j < 8; ++j) {
            float d = sqi[r] + sqj[tx * 8 + j] - 2.f * acc[i][j];
            if (d <= 1.0f) msk |= (1u << j);
        }
        atomicOr(&bw[r][wl], msk << sh);
    }
    __syncthreads();
#pragma unroll
    for (int p = 0; p < 2; ++p) {
        int t2 = tid + p * 256;           // 0..511
        int r = t2 & 127, w2 = t2 >> 7;   // w2 = 0..3
        adj[((size_t)b * 64 + jt * 4 + w2) * N_ + i0 + r] = bw[r][w2];
    }
}

// ---------------------------------------------------------------------------
// Connected components, fused: one block per batch, labels in LDS.
// Per iteration: hook (max over bitset neighbors) + full path compression
// (walk current labels to their fixed point; labels only increase -> always
// terminates). Early-exit when stable; <= ~log N iterations with compression.
// Writes final cluster labels (as float) directly to out.
// ---------------------------------------------------------------------------
__global__ __launch_bounds__(1024)
void cc_kernel(const unsigned* __restrict__ adj, float* __restrict__ out)
{
    __shared__ int Lb[N_];
    __shared__ int chg;
    const int t = threadIdx.x;
    const int b = blockIdx.x;
    const unsigned* ab = adj + (size_t)b * 64 * N_;

    Lb[t] = t; Lb[t + 1024] = t + 1024;
    __syncthreads();

    for (int iter = 0; iter < 24; ++iter) {
        if (t == 0) chg = 0;
        __syncthreads();
        int m[2], o[2];
#pragma unroll
        for (int h = 0; h < 2; ++h) {
            int i = t + h * 1024;
            int mm = Lb[i];
            o[h] = mm;
            const unsigned* row = ab + i;
#pragma unroll 4
            for (int w = 0; w < 64; ++w) {
                unsigned v = row[(size_t)w * N_];
                while (v) {
                    int bit = __ffs(v) - 1;
                    v &= v - 1;
                    int lj = Lb[(w << 5) + bit];
                    mm = (lj > mm) ? lj : mm;
                }
            }
            // full compression: labels strictly increase along the chain
            for (int q = 0; q < N_; ++q) {
                int nx = Lb[mm];
                if (nx == mm) break;
                mm = nx;
            }
            m[h] = mm;
        }
        __syncthreads();
        Lb[t] = m[0]; Lb[t + 1024] = m[1];
        if (m[0] != o[0] || m[1] != o[1]) chg = 1;
        __syncthreads();
        if (!chg) break;
    }
    out[(size_t)b * N_ + t]        = (float)Lb[t];
    out[(size_t)b * N_ + t + 1024] = (float)Lb[t + 1024];
}

__global__ __launch_bounds__(256)
void sentinel_kernel(float* out, int n)
{
    int id = blockIdx.x * 256 + threadIdx.x;
    if (id < n) out[id] = -777.0f;
}

// ---------------------------------------------------------------------------
// Triplet loss: one block per batch; thread t handles triplet t (200 < 256).
// ---------------------------------------------------------------------------
__global__ __launch_bounds__(256)
void loss_kernel(const float* __restrict__ u, const float* __restrict__ sq,
                 const int* __restrict__ labels, const int* __restrict__ tri,
                 float* __restrict__ loss)
{
    __shared__ float ssum[256];
    __shared__ int   scnt[256];
    __shared__ int   smax[256];
    const int b = blockIdx.x, t = threadIdx.x;
    const int base = b << 11;

    float mysum = 0.f; int mycnt = 0;
    if (t < 200) {
        int a = tri[3*t+0], p = tri[3*t+1], n = tri[3*t+2];
        int la = labels[base+a], lp = labels[base+p], ln = labels[base+n];
        bool valid = (a != p) && (la == lp) && (lp != ln);
        const float4* ua = (const float4*)(u + (size_t)(base + a) * F3_);
        const float4* up = (const float4*)(u + (size_t)(base + p) * F3_);
        const float4* un = (const float4*)(u + (size_t)(base + n) * F3_);
        float dap = 0.f, dan = 0.f;
#pragma unroll
        for (int q = 0; q < 16; ++q) {
            float4 va = ua[q], vp = up[q], vn = un[q];
            dap += va.x*vp.x + va.y*vp.y + va.z*vp.z + va.w*vp.w;
            dan += va.x*vn.x + va.y*vn.y + va.z*vn.z + va.w*vn.w;
        }
        float d1 = fmaxf(sq[base+a] + sq[base+p] - 2.f*dap, 0.f);
        float d2 = fmaxf(sq[base+a] + sq[base+n] - 2.f*dan, 0.f);
        float tt = fmaxf(d1 - d2 + 2.0f, 0.f);
        if (valid) { mysum = tt; mycnt = 1; }
    }
    int mymax = 0;
    for (int idx = t; idx < N_; idx += 256) {
        int lv = labels[base + idx];
        mymax = (lv > mymax) ? lv : mymax;
    }
    ssum[t] = mysum; scnt[t] = mycnt; smax[t] = mymax;
    __syncthreads();
    for (int s = 128; s > 0; s >>= 1) {
        if (t < s) {
            ssum[t] += ssum[t + s];
            scnt[t] += scnt[t + s];
            smax[t] = (smax[t + s] > smax[t]) ? smax[t + s] : smax[t];
        }
        __syncthreads();
    }
    if (t == 0) {
        int cnt = scnt[0];
        bool use = (smax[0] > 0) && (cnt > 0);
        float contrib = use ? (ssum[0] / (float)(cnt > 1 ? cnt : 1)) : 0.f;
        atomicAdd(loss, contrib);
    }
}

// ---------------------------------------------------------------------------
extern "C" void kernel_launch(void* const* d_in, const int* in_sizes, int n_in,
                              void* d_out, int out_size, void* d_ws, size_t ws_size,
                              hipStream_t stream)
{
    const float* x      = (const float*)d_in[0];
    const int*   labels = (const int*)  d_in[1];
    const int*   tri    = (const int*)  d_in[2];
    const float* W1     = (const float*)d_in[3];
    const float* b1     = (const float*)d_in[4];
    const float* W2     = (const float*)d_in[5];
    const float* b2     = (const float*)d_in[6];
    const float* W3     = (const float*)d_in[7];
    const float* b3     = (const float*)d_in[8];
    float* out = (float*)d_out;

    char* w = (char*)d_ws;
    size_t off = 0;
    auto carve = [&](size_t bytes) -> char* {
        char* p = w + off;
        off += (bytes + 255) & ~(size_t)255;
        return p;
    };
    float*    h1  = (float*)   carve((size_t)M_ * F1_ * 4);
    float*    h2  = (float*)   carve((size_t)M_ * F2_ * 4);
    float*    u   = (float*)   carve((size_t)M_ * F3_ * 4);
    float*    sq  = (float*)   carve((size_t)M_ * 4);
    unsigned* adj = (unsigned*)carve((size_t)B_ * 64 * N_ * 4);

    if (off > ws_size) {
        hipLaunchKernelGGL(sentinel_kernel, dim3((out_size + 255) / 256), dim3(256),
                           0, stream, out, out_size);
        return;
    }

    hipLaunchKernelGGL((gemm_bias_act<128,1>), dim3(F1_/128, M_/128), dim3(256), 0, stream,
                       x,  W1, b1, h1, CIN_, F1_);
    hipLaunchKernelGGL((gemm_bias_act<128,1>), dim3(F2_/128, M_/128), dim3(256), 0, stream,
                       h1, W2, b2, h2, F1_,  F2_);
    hipLaunchKernelGGL((gemm_bias_act<64,0>),  dim3(F3_/64,  M_/128), dim3(256), 0, stream,
                       h2, W3, b3, u,  F2_,  F3_);

    hipLaunchKernelGGL(sq_loss_init, dim3(M_/256), dim3(256), 0, stream,
                       u, sq, out + M_);

    hipLaunchKernelGGL(adj_kernel, dim3(N_/128, N_/128, B_), dim3(256), 0, stream,
                       u, sq, adj);

    hipLaunchKernelGGL(loss_kernel, dim3(B_), dim3(256), 0, stream,
                       u, sq, labels, tri, out + M_);

    hipLaunchKernelGGL(cc_kernel, dim3(B_), dim3(1024), 0, stream,
                       adj, out);
}

// Round 4
// 240.117 us; speedup vs baseline: 1.4323x; 1.0714x over previous
//
#include <hip/hip_runtime.h>

// Problem constants (fixed by reference)
constexpr int B_   = 8;
constexpr int N_   = 2048;
constexpr int CIN_ = 128;
constexpr int F1_  = 256;
constexpr int F2_  = 256;
constexpr int F3_  = 64;
constexpr int M_   = B_ * N_;   // 16384 tokens

typedef __attribute__((ext_vector_type(8)))  short short8v;   // 8 bf16 (4 VGPRs)
typedef __attribute__((ext_vector_type(16))) float f32x16;    // MFMA 32x32 acc

// bf16 round-to-nearest-even helpers (bit-level, no header type friction)
__device__ inline unsigned short f2bf(float x){
    union { float f; unsigned u; } c; c.f = x;
    unsigned r = (c.u + 0x7FFFu + ((c.u >> 16) & 1u)) >> 16;
    return (unsigned short)r;
}
__device__ inline float bf2f(unsigned short h){
    union { unsigned u; float f; } c; c.u = ((unsigned)h) << 16;
    return c.f;
}

// ---------------------------------------------------------------------------
// GEMM: C[m][f] = act( sum_k A[m][k] * W[f][k] + bias[f] )
// 128xTF tile, BK=32, 256 threads, 8x(TF/16) register tile per thread.
// lz != nullptr -> one thread zeroes the loss accumulator (saves a kernel).
// ---------------------------------------------------------------------------
template<int TF, int RELU>
__global__ __launch_bounds__(256, 4)
void gemm_bias_act(const float* __restrict__ A, const float* __restrict__ W,
                   const float* __restrict__ bias, float* __restrict__ C,
                   int K, int F, float* lz)
{
    constexpr int WF = TF / 16;
    __shared__ __align__(16) float As[32][132];
    __shared__ __align__(16) float Ws[32][TF + 4];
    const int tid = threadIdx.x;
    const int tx = tid & 15, ty = tid >> 4;
    const int m0 = blockIdx.y * 128, f0 = blockIdx.x * TF;
    if (lz && tid == 0 && blockIdx.x == 0 && blockIdx.y == 0) *lz = 0.f;

    float acc[8][WF] = {};
    for (int k0 = 0; k0 < K; k0 += 32) {
        __syncthreads();
#pragma unroll
        for (int p = 0; p < 4; ++p) {
            int idx = tid + p * 256;
            int r = idx >> 3, c = (idx & 7) << 2;
            float4 v = *(const float4*)(A + (size_t)(m0 + r) * K + k0 + c);
            As[c+0][r] = v.x; As[c+1][r] = v.y; As[c+2][r] = v.z; As[c+3][r] = v.w;
        }
#pragma unroll
        for (int p = 0; p < TF / 32; ++p) {
            int idx = tid + p * 256;
            int r = idx >> 3, c = (idx & 7) << 2;
            float4 v = *(const float4*)(W + (size_t)(f0 + r) * K + k0 + c);
            Ws[c+0][r] = v.x; Ws[c+1][r] = v.y; Ws[c+2][r] = v.z; Ws[c+3][r] = v.w;
        }
        __syncthreads();
#pragma unroll
        for (int k = 0; k < 32; ++k) {
            float a[8], w[WF];
            *(float4*)&a[0] = *(const float4*)&As[k][ty * 8];
            *(float4*)&a[4] = *(const float4*)&As[k][ty * 8 + 4];
            *(float4*)&w[0] = *(const float4*)&Ws[k][tx * WF];
            if constexpr (WF == 8)
                *(float4*)&w[4] = *(const float4*)&Ws[k][tx * WF + 4];
#pragma unroll
            for (int i = 0; i < 8; ++i)
#pragma unroll
                for (int j = 0; j < WF; ++j)
                    acc[i][j] = fmaf(a[i], w[j], acc[i][j]);
        }
    }
    float bz[WF];
    *(float4*)&bz[0] = *(const float4*)(bias + f0 + tx * WF);
    if constexpr (WF == 8)
        *(float4*)&bz[4] = *(const float4*)(bias + f0 + tx * WF + 4);
#pragma unroll
    for (int i = 0; i < 8; ++i) {
        float o[WF];
#pragma unroll
        for (int j = 0; j < WF; ++j) {
            o[j] = acc[i][j] + bz[j];
            if (RELU) o[j] = fmaxf(o[j], 0.f);
        }
        float* cp = C + (size_t)(m0 + ty * 8 + i) * F + f0 + tx * WF;
        *(float4*)cp = *(const float4*)&o[0];
        if constexpr (WF == 8)
            *(float4*)(cp + 4) = *(const float4*)&o[4];
    }
}

// ---------------------------------------------------------------------------
// Layer-3 GEMM fused with: u (fp32), u_hi/u_lo (bf16 split, stored in the
// XOR-swizzled slot layout adj wants), and sq = rowwise ||u||^2 (shfl reduce).
// TF = 64 covers the whole feature dim -> each block owns complete rows.
// ---------------------------------------------------------------------------
__global__ __launch_bounds__(256, 4)
void gemm3_fused(const float* __restrict__ A, const float* __restrict__ W,
                 const float* __restrict__ bias, float* __restrict__ C,
                 unsigned short* __restrict__ uh, unsigned short* __restrict__ ul,
                 float* __restrict__ sqv)
{
    constexpr int K = 256;
    __shared__ __align__(16) float As[32][132];
    __shared__ __align__(16) float Ws[32][68];
    const int tid = threadIdx.x;
    const int tx = tid & 15, ty = tid >> 4;
    const int m0 = blockIdx.y * 128;

    float acc[8][4] = {};
    for (int k0 = 0; k0 < K; k0 += 32) {
        __syncthreads();
#pragma unroll
        for (int p = 0; p < 4; ++p) {
            int idx = tid + p * 256;
            int r = idx >> 3, c = (idx & 7) << 2;
            float4 v = *(const float4*)(A + (size_t)(m0 + r) * K + k0 + c);
            As[c+0][r] = v.x; As[c+1][r] = v.y; As[c+2][r] = v.z; As[c+3][r] = v.w;
        }
#pragma unroll
        for (int p = 0; p < 2; ++p) {
            int idx = tid + p * 256;
            int r = idx >> 3, c = (idx & 7) << 2;
            float4 v = *(const float4*)(W + (size_t)r * K + k0 + c);
            Ws[c+0][r] = v.x; Ws[c+1][r] = v.y; Ws[c+2][r] = v.z; Ws[c+3][r] = v.w;
        }
        __syncthreads();
#pragma unroll
        for (int k = 0; k < 32; ++k) {
            float a[8], w[4];
            *(float4*)&a[0] = *(const float4*)&As[k][ty * 8];
            *(float4*)&a[4] = *(const float4*)&As[k][ty * 8 + 4];
            *(float4*)&w[0] = *(const float4*)&Ws[k][tx * 4];
#pragma unroll
            for (int i = 0; i < 8; ++i)
#pragma unroll
                for (int j = 0; j < 4; ++j)
                    acc[i][j] = fmaf(a[i], w[j], acc[i][j]);
        }
    }
    float4 bz = *(const float4*)(bias + tx * 4);
    const int slot = tx >> 1;              // 16B slot (8 bf16) 0..7
    const int hoff = (tx & 1) * 4;         // ushort offset within slot
#pragma unroll
    for (int i = 0; i < 8; ++i) {
        const int m = m0 + ty * 8 + i;
        float o[4];
        o[0] = acc[i][0] + bz.x; o[1] = acc[i][1] + bz.y;
        o[2] = acc[i][2] + bz.z; o[3] = acc[i][3] + bz.w;
        *(float4*)(C + (size_t)m * F3_ + tx * 4) = *(const float4*)&o[0];
        ushort4 h4, l4;
        h4.x = f2bf(o[0]); l4.x = f2bf(o[0] - bf2f(h4.x));
        h4.y = f2bf(o[1]); l4.y = f2bf(o[1] - bf2f(h4.y));
        h4.z = f2bf(o[2]); l4.z = f2bf(o[2] - bf2f(h4.z));
        h4.w = f2bf(o[3]); l4.w = f2bf(o[3] - bf2f(h4.w));
        const int sb = (((slot * 16) ^ ((m & 7) << 4)) >> 1) + hoff;
        *(ushort4*)&uh[(size_t)m * 64 + sb] = h4;
        *(ushort4*)&ul[(size_t)m * 64 + sb] = l4;
        float s = o[0]*o[0] + o[1]*o[1] + o[2]*o[2] + o[3]*o[3];
#pragma unroll
        for (int msk = 1; msk <= 8; msk <<= 1) s += __shfl_xor(s, msk, 64);
        if (tx == 0) sqv[m] = s;
    }
}

// ---------------------------------------------------------------------------
// Adjacency via split-bf16 MFMA: bit(b,i,j) = (sq_i + sq_j - 2 dot <= 1).
// 128x128 tile, 4 waves each owning a 64x64 quadrant (2x2 of 32x32 MFMAs).
// dot = hi.hi + hi.lo + lo.hi (3 MFMAs, fp32 acc). Lanes with |d-1| < 0.02
// recompute exact fp32 from u (same fmaf order that passed at absmax 0).
// Bit-pack: one __ballot per acc reg = two 32-bit adjacency words.
// ---------------------------------------------------------------------------
__global__ __launch_bounds__(256)
void adj_mfma(const unsigned short* __restrict__ uh,
              const unsigned short* __restrict__ ul,
              const float* __restrict__ uf, const float* __restrict__ sqv,
              unsigned* __restrict__ adj)
{
    __shared__ unsigned short UiH[128*64], UiL[128*64];
    __shared__ unsigned short UjH[128*64], UjL[128*64];
    __shared__ float sqi[128], sqj[128];
    const int tid = threadIdx.x;
    const int jt = blockIdx.x, it = blockIdx.y, b = blockIdx.z;
    const int i0 = it * 128, j0 = jt * 128;
    const size_t ub = (size_t)b * N_;

    if (tid < 128) sqi[tid] = sqv[ub + i0 + tid];
    else           sqj[tid - 128] = sqv[ub + j0 + (tid - 128)];

    auto stage = [&](const unsigned short* src, unsigned short* dst) {
#pragma unroll
        for (int p = 0; p < 4; ++p) {
            int g = tid + p * 256;     // 16B group, 1024 per array
            *(short8v*)&dst[g * 8] = *(const short8v*)&src[g * 8];
        }
    };
    stage(uh + (ub + i0) * 64, UiH);
    stage(ul + (ub + i0) * 64, UiL);
    stage(uh + (ub + j0) * 64, UjH);
    stage(ul + (ub + j0) * 64, UjL);
    __syncthreads();

    const int w  = tid >> 6, l = tid & 63;
    const int wr = w >> 1,  wc = w & 1;
    const int lr = l & 31,  hl = l >> 5;

    f32x16 acc[2][2] = {};
    auto frag = [&](const unsigned short* arr, int row, int kb) -> short8v {
        int off = row * 64 + ((kb ^ ((row & 7) << 4)) >> 1);
        return *(const short8v*)&arr[off];
    };
#pragma unroll
    for (int ks = 0; ks < 4; ++ks) {
        const int kb = ks * 32 + hl * 16;
        short8v aH[2], aL[2], bH[2], bL[2];
#pragma unroll
        for (int ri = 0; ri < 2; ++ri) {
            aH[ri] = frag(UiH, wr * 64 + ri * 32 + lr, kb);
            aL[ri] = frag(UiL, wr * 64 + ri * 32 + lr, kb);
        }
#pragma unroll
        for (int ci = 0; ci < 2; ++ci) {
            bH[ci] = frag(UjH, wc * 64 + ci * 32 + lr, kb);
            bL[ci] = frag(UjL, wc * 64 + ci * 32 + lr, kb);
        }
#pragma unroll
        for (int ri = 0; ri < 2; ++ri)
#pragma unroll
            for (int ci = 0; ci < 2; ++ci) {
                acc[ri][ci] = __builtin_amdgcn_mfma_f32_32x32x16_bf16(aH[ri], bH[ci], acc[ri][ci], 0, 0, 0);
                acc[ri][ci] = __builtin_amdgcn_mfma_f32_32x32x16_bf16(aH[ri], bL[ci], acc[ri][ci], 0, 0, 0);
                acc[ri][ci] = __builtin_amdgcn_mfma_f32_32x32x16_bf16(aL[ri], bH[ci], acc[ri][ci], 0, 0, 0);
            }
    }

#pragma unroll
    for (int ri = 0; ri < 2; ++ri)
#pragma unroll
    for (int ci = 0; ci < 2; ++ci) {
        const int Rb = wr * 64 + ri * 32;
        const int Cb = wc * 64 + ci * 32;
        const int jloc = Cb + lr;
        const float sj = sqj[jloc];
#pragma unroll
        for (int r = 0; r < 16; ++r) {
            const int base = (r & 3) + 8 * (r >> 2);
            const int iloc = Rb + base + 4 * hl;
            const float si = sqi[iloc];
            float dv = si + sj - 2.0f * acc[ri][ci][r];
            bool e;
            if (__builtin_expect(fabsf(dv - 1.0f) < 0.02f, 0)) {
                const float* ua = uf + (ub + i0 + iloc) * (size_t)F3_;
                const float* vb = uf + (ub + j0 + jloc) * (size_t)F3_;
                float dot = 0.f;
#pragma unroll 4
                for (int k = 0; k < F3_; ++k) dot = fmaf(ua[k], vb[k], dot);
                e = (si + sj - 2.0f * dot) <= 1.0f;
            } else {
                e = dv <= 1.0f;
            }
            unsigned long long m = __ballot(e);
            if (l == 0) {
                const int I = i0 + Rb + base;          // hl=0 rows
                const int W = (j0 + Cb) >> 5;
                adj[((size_t)b * 64 + W) * N_ + I]     = (unsigned)m;
                adj[((size_t)b * 64 + W) * N_ + I + 4] = (unsigned)(m >> 32);
            }
        }
    }
}

// ---------------------------------------------------------------------------
// Connected components, fused: one block per batch, labels in LDS.
// hook (max over bitset neighbors) + full path compression, early exit.
// ---------------------------------------------------------------------------
__global__ __launch_bounds__(1024)
void cc_kernel(const unsigned* __restrict__ adj, float* __restrict__ out)
{
    __shared__ int Lb[N_];
    __shared__ int chg;
    const int t = threadIdx.x;
    const int b = blockIdx.x;
    const unsigned* ab = adj + (size_t)b * 64 * N_;

    Lb[t] = t; Lb[t + 1024] = t + 1024;
    __syncthreads();

    for (int iter = 0; iter < 24; ++iter) {
        if (t == 0) chg = 0;
        __syncthreads();
        int m[2], o[2];
#pragma unroll
        for (int h = 0; h < 2; ++h) {
            int i = t + h * 1024;
            int mm = Lb[i];
            o[h] = mm;
            const unsigned* row = ab + i;
#pragma unroll 4
            for (int w = 0; w < 64; ++w) {
                unsigned v = row[(size_t)w * N_];
                while (v) {
                    int bit = __ffs(v) - 1;
                    v &= v - 1;
                    int lj = Lb[(w << 5) + bit];
                    mm = (lj > mm) ? lj : mm;
                }
            }
            for (int q = 0; q < N_; ++q) {
                int nx = Lb[mm];
                if (nx == mm) break;
                mm = nx;
            }
            m[h] = mm;
        }
        __syncthreads();
        Lb[t] = m[0]; Lb[t + 1024] = m[1];
        if (m[0] != o[0] || m[1] != o[1]) chg = 1;
        __syncthreads();
        if (!chg) break;
    }
    out[(size_t)b * N_ + t]        = (float)Lb[t];
    out[(size_t)b * N_ + t + 1024] = (float)Lb[t + 1024];
}

__global__ __launch_bounds__(256)
void sentinel_kernel(float* out, int n)
{
    int id = blockIdx.x * 256 + threadIdx.x;
    if (id < n) out[id] = -777.0f;
}

// ---------------------------------------------------------------------------
// Triplet loss: one block per batch; thread t handles triplet t (200 < 256).
// ---------------------------------------------------------------------------
__global__ __launch_bounds__(256)
void loss_kernel(const float* __restrict__ u, const float* __restrict__ sq,
                 const int* __restrict__ labels, const int* __restrict__ tri,
                 float* __restrict__ loss)
{
    __shared__ float ssum[256];
    __shared__ int   scnt[256];
    __shared__ int   smax[256];
    const int b = blockIdx.x, t = threadIdx.x;
    const int base = b << 11;

    float mysum = 0.f; int mycnt = 0;
    if (t < 200) {
        int a = tri[3*t+0], p = tri[3*t+1], n = tri[3*t+2];
        int la = labels[base+a], lp = labels[base+p], ln = labels[base+n];
        bool valid = (a != p) && (la == lp) && (lp != ln);
        const float4* ua = (const float4*)(u + (size_t)(base + a) * F3_);
        const float4* up = (const float4*)(u + (size_t)(base + p) * F3_);
        const float4* un = (const float4*)(u + (size_t)(base + n) * F3_);
        float dap = 0.f, dan = 0.f;
#pragma unroll
        for (int q = 0; q < 16; ++q) {
            float4 va = ua[q], vp = up[q], vn = un[q];
            dap += va.x*vp.x + va.y*vp.y + va.z*vp.z + va.w*vp.w;
            dan += va.x*vn.x + va.y*vn.y + va.z*vn.z + va.w*vn.w;
        }
        float d1 = fmaxf(sq[base+a] + sq[base+p] - 2.f*dap, 0.f);
        float d2 = fmaxf(sq[base+a] + sq[base+n] - 2.f*dan, 0.f);
        float tt = fmaxf(d1 - d2 + 2.0f, 0.f);
        if (valid) { mysum = tt; mycnt = 1; }
    }
    int mymax = 0;
    for (int idx = t; idx < N_; idx += 256) {
        int lv = labels[base + idx];
        mymax = (lv > mymax) ? lv : mymax;
    }
    ssum[t] = mysum; scnt[t] = mycnt; smax[t] = mymax;
    __syncthreads();
    for (int s = 128; s > 0; s >>= 1) {
        if (t < s) {
            ssum[t] += ssum[t + s];
            scnt[t] += scnt[t + s];
            smax[t] = (smax[t + s] > smax[t]) ? smax[t + s] : smax[t];
        }
        __syncthreads();
    }
    if (t == 0) {
        int cnt = scnt[0];
        bool use = (smax[0] > 0) && (cnt > 0);
        float contrib = use ? (ssum[0] / (float)(cnt > 1 ? cnt : 1)) : 0.f;
        atomicAdd(loss, contrib);
    }
}

// ---------------------------------------------------------------------------
extern "C" void kernel_launch(void* const* d_in, const int* in_sizes, int n_in,
                              void* d_out, int out_size, void* d_ws, size_t ws_size,
                              hipStream_t stream)
{
    const float* x      = (const float*)d_in[0];
    const int*   labels = (const int*)  d_in[1];
    const int*   tri    = (const int*)  d_in[2];
    const float* W1     = (const float*)d_in[3];
    const float* b1     = (const float*)d_in[4];
    const float* W2     = (const float*)d_in[5];
    const float* b2     = (const float*)d_in[6];
    const float* W3     = (const float*)d_in[7];
    const float* b3     = (const float*)d_in[8];
    float* out = (float*)d_out;

    char* w = (char*)d_ws;
    size_t off = 0;
    auto carve = [&](size_t bytes) -> char* {
        char* p = w + off;
        off += (bytes + 255) & ~(size_t)255;
        return p;
    };
    float*          h1  = (float*)         carve((size_t)M_ * F1_ * 4);
    float*          h2  = (float*)         carve((size_t)M_ * F2_ * 4);
    float*          u   = (float*)         carve((size_t)M_ * F3_ * 4);
    unsigned short* uh  = (unsigned short*)carve((size_t)M_ * F3_ * 2);
    unsigned short* ul  = (unsigned short*)carve((size_t)M_ * F3_ * 2);
    float*          sq  = (float*)         carve((size_t)M_ * 4);
    unsigned*       adj = (unsigned*)      carve((size_t)B_ * 64 * N_ * 4);

    if (off > ws_size) {
        hipLaunchKernelGGL(sentinel_kernel, dim3((out_size + 255) / 256), dim3(256),
                           0, stream, out, out_size);
        return;
    }

    hipLaunchKernelGGL((gemm_bias_act<128,1>), dim3(F1_/128, M_/128), dim3(256), 0, stream,
                       x,  W1, b1, h1, CIN_, F1_, out + M_);
    hipLaunchKernelGGL((gemm_bias_act<128,1>), dim3(F2_/128, M_/128), dim3(256), 0, stream,
                       h1, W2, b2, h2, F1_,  F2_, (float*)nullptr);
    hipLaunchKernelGGL(gemm3_fused, dim3(1, M_/128), dim3(256), 0, stream,
                       h2, W3, b3, u, uh, ul, sq);

    hipLaunchKernelGGL(adj_mfma, dim3(N_/128, N_/128, B_), dim3(256), 0, stream,
                       uh, ul, u, sq, adj);

    hipLaunchKernelGGL(loss_kernel, dim3(B_), dim3(256), 0, stream,
                       u, sq, labels, tri, out + M_);

    hipLaunchKernelGGL(cc_kernel, dim3(B_), dim3(1024), 0, stream,
                       adj, out);
}